// Round 1
// baseline (6335.379 us; speedup 1.0000x reference)
//
#include <hip/hip_runtime.h>

// D-MPNN (chemprop) x3 encoders on MI355X.
// Key algebra: h_nei@Ur == (h@Ur)[bgraph]  (6x FLOP cut);
// hmess@W terms hoisted out of the depth loop (zpre/hpre/r1b).
// All GEMMs: bf16 MFMA 16x16x32, fp32 accum. Weights pre-packed fragment-major.

#define NE 100000   // messages
#define NN 50000    // nodes
#define HD 256      // hidden

typedef unsigned short u16;
typedef short short8 __attribute__((ext_vector_type(8)));
typedef float f32x4 __attribute__((ext_vector_type(4)));
typedef unsigned short u16x4 __attribute__((ext_vector_type(4)));

__device__ __forceinline__ float b2f(u16 u) {
  union { unsigned int i; float f; } v; v.i = ((unsigned int)u) << 16; return v.f;
}
__device__ __forceinline__ u16 f2b(float f) {
  union { float f; unsigned int i; } v; v.f = f;
  unsigned int b = v.i;
  b += 0x7FFFu + ((b >> 16) & 1u);   // RTNE
  return (u16)(b >> 16);
}
__device__ __forceinline__ float sigm(float x) { return 1.0f / (1.0f + __expf(-x)); }
__device__ __forceinline__ float tanh_f(float x) { return 2.0f / (1.0f + __expf(-2.0f * x)) - 1.0f; }
__device__ __forceinline__ f32x4 mfma16(short8 a, short8 b, f32x4 c) {
  return __builtin_amdgcn_mfma_f32_16x16x32_bf16(a, b, c, 0, 0, 0);
}

// ---------------- weight packing (fragment-major) ----------------
// Packed B layout: elem j of lane l at ((s*NB16 + nb)*64 + l)*8 + j
// holds W[32*s + 8*(l>>4) + j][16*nb + (l&15)].  Same k-mapping as A-frag
// loads, so any HW K-slot permutation cancels.

__global__ void pack_wpre(const float* __restrict__ Wr, const float* __restrict__ Wz,
                          const float* __restrict__ Wh, u16* __restrict__ dst) {
  const int g = blockIdx.y;
  const int p = blockIdx.x * 256 + threadIdx.x;           // < 98304  (K=128,N=768)
  const int j = p & 7, l = (p >> 3) & 63, q = p >> 9;
  const int nb = q % 48, s = q / 48;
  const int k = 32 * s + 8 * (l >> 4) + j;
  const int n = 16 * nb + (l & 15);
  float v = 0.f;
  if (k < 104) {
    if (n < 256)      v = Wr[((size_t)g * 104 + k) * 256 + n];
    else if (n < 512) v = Wz[((size_t)g * 360 + k) * 256 + (n - 256)];
    else              v = Wh[((size_t)g * 360 + k) * 256 + (n - 512)];
  }
  dst[(size_t)g * 98304 + p] = f2b(v);
}

__global__ void pack_wgate(const float* __restrict__ Wz, const float* __restrict__ Wh,
                           u16* __restrict__ dst) {
  const int g = blockIdx.y;
  const int p = blockIdx.x * 256 + threadIdx.x;           // < 131072 (K=256,N=512)
  const int j = p & 7, l = (p >> 3) & 63, q = p >> 9;
  const int nb = q % 32, s = q / 32;
  const int k = 32 * s + 8 * (l >> 4) + j;
  const int n = 16 * nb + (l & 15);
  float v = (n < 256) ? Wz[((size_t)g * 360 + 104 + k) * 256 + n]
                      : Wh[((size_t)g * 360 + 104 + k) * 256 + (n - 256)];
  dst[(size_t)g * 131072 + p] = f2b(v);
}

__global__ void pack_ur(const float* __restrict__ Ur, u16* __restrict__ dst) {
  const int g = blockIdx.y;
  const int p = blockIdx.x * 256 + threadIdx.x;           // < 65536 (K=256,N=256)
  const int j = p & 7, l = (p >> 3) & 63, q = p >> 9;
  const int nb = q % 16, s = q / 16;
  const int k = 32 * s + 8 * (l >> 4) + j;
  const int n = 16 * nb + (l & 15);
  dst[(size_t)g * 65536 + p] = f2b(Ur[((size_t)g * 256 + k) * 256 + n]);
}

__global__ void pack_wo(const float* __restrict__ Wo, u16* __restrict__ dst) {
  const int g = blockIdx.y;
  const int p = blockIdx.x * 256 + threadIdx.x;           // < 98304 (K=384,N=256)
  const int j = p & 7, l = (p >> 3) & 63, q = p >> 9;
  const int nb = q % 16, s = q / 16;
  const int k = 32 * s + 8 * (l >> 4) + j;
  const int n = 16 * nb + (l & 15);
  float v = 0.f;
  if (k < 98)        v = Wo[((size_t)g * 354 + k) * 256 + n];        // fnode part
  else if (k >= 128) v = Wo[((size_t)g * 354 + (k - 30)) * 256 + n]; // nei part
  dst[(size_t)g * 98304 + p] = f2b(v);
}

// ---------------- embeddings ----------------
__global__ void embed_hmess(const float* __restrict__ fnode, const int* __restrict__ fmess_idx,
                            const float* __restrict__ fmess_feat, u16* __restrict__ hmess) {
  const int e = blockIdx.x * 2 + (threadIdx.x >> 7);
  const int c = threadIdx.x & 127;
  const int src = fmess_idx[e * 2];
  float v = 0.f;
  if (c < 98)       v = fnode[(size_t)src * 98 + c];
  else if (c < 104) v = fmess_feat[(size_t)e * 6 + (c - 98)];
  hmess[(size_t)e * 128 + c] = f2b(v);
}

__global__ void embed_fnode(const float* __restrict__ fnode, u16* __restrict__ fnp) {
  const int n = blockIdx.x * 2 + (threadIdx.x >> 7);
  const int c = threadIdx.x & 127;
  float v = (c < 98) ? fnode[(size_t)n * 98 + c] : 0.f;
  fnp[(size_t)n * 128 + c] = f2b(v);
}

// ---------------- pre-GEMM: pre[E][768] = hmess[E][128] @ Wpre + bias ----------------
// cols 0..255 = r1b (=hmess@Wr+bur), 256..511 = zpre (+bz), 512..767 = hpre (+bh)
__global__ __launch_bounds__(256)
void pre_gemm(const u16* __restrict__ hmess, const u16* __restrict__ Wpre,
              const float* __restrict__ bur, const float* __restrict__ bz,
              const float* __restrict__ bh, u16* __restrict__ pre) {
  const int tid = threadIdx.x, wave = tid >> 6, lane = tid & 63;
  const int e0 = blockIdx.x * 32;
  const int cchunk = blockIdx.y;                  // 0..2 -> 256-col chunk
  const int row0 = lane & 15, kq = lane >> 4;
  f32x4 acc[2][4];
#pragma unroll
  for (int i = 0; i < 2; ++i)
#pragma unroll
    for (int n = 0; n < 4; ++n) { acc[i][n][0]=0.f; acc[i][n][1]=0.f; acc[i][n][2]=0.f; acc[i][n][3]=0.f; }
#pragma unroll
  for (int s = 0; s < 4; ++s) {
    short8 a0 = *(const short8*)(hmess + (size_t)(e0 + row0) * 128 + s * 32 + kq * 8);
    short8 a1 = *(const short8*)(hmess + (size_t)(e0 + 16 + row0) * 128 + s * 32 + kq * 8);
#pragma unroll
    for (int ni = 0; ni < 4; ++ni) {
      const int nb = cchunk * 16 + wave * 4 + ni;
      short8 b = *(const short8*)(Wpre + ((size_t)(s * 48 + nb) * 64 + lane) * 8);
      acc[0][ni] = mfma16(a0, b, acc[0][ni]);
      acc[1][ni] = mfma16(a1, b, acc[1][ni]);
    }
  }
  const float* bias = (cchunk == 0) ? bur : (cchunk == 1 ? bz : bh);
#pragma unroll
  for (int mi = 0; mi < 2; ++mi)
#pragma unroll
    for (int ni = 0; ni < 4; ++ni)
#pragma unroll
      for (int v = 0; v < 4; ++v) {
        const int m = mi * 16 + kq * 4 + v;
        const int col = cchunk * 256 + wave * 64 + ni * 16 + row0;
        const int e = e0 + m;
        pre[(size_t)e * 768 + col] = f2b(acc[mi][ni][v] + bias[col & 255]);
      }
}

// ---------------- fused depth step ----------------
// HB layout: [E][512] bf16 : cols 0..255 = h, 256..511 = hu (= h @ Ur)
template <int FIRST>
__global__ __launch_bounds__(256)
void mpn_step(const u16* __restrict__ HBin, u16* __restrict__ HBout,
              const u16* __restrict__ pre, const int* __restrict__ bgraph,
              const u16* __restrict__ Wgate, const u16* __restrict__ Urp) {
  __shared__ __align__(16) u16 sA[2][32][264];   // [0]=sum_h, [1]=sum_gh then hnew
  const int tid = threadIdx.x, wave = tid >> 6, lane = tid & 63;
  const int e0 = blockIdx.x * 32;
  const int row0 = lane & 15, kq = lane >> 4;

  if (!FIRST) {
    // gather: sum_h, sum_gh = sum_n sigmoid(r1b + hu_nei) * h_nei
#pragma unroll 2
    for (int rr = 0; rr < 8; ++rr) {
      const int r = wave * 8 + rr;
      const int e = e0 + r;
      const u16x4 r1v = *(const u16x4*)(pre + (size_t)e * 768 + 4 * lane);
      float r1f[4], sh[4] = {0.f, 0.f, 0.f, 0.f}, sg[4] = {0.f, 0.f, 0.f, 0.f};
#pragma unroll
      for (int j = 0; j < 4; ++j) r1f[j] = b2f(r1v[j]);
#pragma unroll
      for (int nb = 0; nb < 6; ++nb) {
        const int idx = bgraph[e * 6 + nb];
        const u16* row = HBin + (size_t)idx * 512;
        const u16x4 hv  = *(const u16x4*)(row + 4 * lane);
        const u16x4 huv = *(const u16x4*)(row + 256 + 4 * lane);
#pragma unroll
        for (int j = 0; j < 4; ++j) {
          const float h = b2f(hv[j]);
          const float rg = sigm(r1f[j] + b2f(huv[j]));
          sh[j] += h;
          sg[j] += rg * h;
        }
      }
#pragma unroll
      for (int j = 0; j < 4; ++j) {
        sA[0][r][4 * lane + j] = f2b(sh[j]);
        sA[1][r][4 * lane + j] = f2b(sg[j]);
      }
    }
  }
  __syncthreads();

  f32x4 accZ[2][4], accH[2][4];
#pragma unroll
  for (int i = 0; i < 2; ++i)
#pragma unroll
    for (int n = 0; n < 4; ++n) {
      accZ[i][n][0]=0.f; accZ[i][n][1]=0.f; accZ[i][n][2]=0.f; accZ[i][n][3]=0.f;
      accH[i][n][0]=0.f; accH[i][n][1]=0.f; accH[i][n][2]=0.f; accH[i][n][3]=0.f;
    }

  if (!FIRST) {
    // gz = sum_h @ Wz2 ; gh = sum_gh @ Wh2  (B frags direct from L2)
#pragma unroll
    for (int s = 0; s < 8; ++s) {
      short8 ah0 = *(const short8*)&sA[0][row0][s * 32 + kq * 8];
      short8 ah1 = *(const short8*)&sA[0][row0 + 16][s * 32 + kq * 8];
      short8 ag0 = *(const short8*)&sA[1][row0][s * 32 + kq * 8];
      short8 ag1 = *(const short8*)&sA[1][row0 + 16][s * 32 + kq * 8];
#pragma unroll
      for (int ni = 0; ni < 4; ++ni) {
        const int nbz = wave * 4 + ni;
        short8 bz_ = *(const short8*)(Wgate + ((size_t)(s * 32 + nbz) * 64 + lane) * 8);
        short8 bh_ = *(const short8*)(Wgate + ((size_t)(s * 32 + 16 + nbz) * 64 + lane) * 8);
        accZ[0][ni] = mfma16(ah0, bz_, accZ[0][ni]);
        accZ[1][ni] = mfma16(ah1, bz_, accZ[1][ni]);
        accH[0][ni] = mfma16(ag0, bh_, accH[0][ni]);
        accH[1][ni] = mfma16(ag1, bh_, accH[1][ni]);
      }
    }
    __syncthreads();   // protect sA[1] overwrite below
  }

  // GRU update epilogue; stash hnew into sA[1] for the Ur GEMM
#pragma unroll
  for (int mi = 0; mi < 2; ++mi)
#pragma unroll
    for (int ni = 0; ni < 4; ++ni)
#pragma unroll
      for (int v = 0; v < 4; ++v) {
        const int m = mi * 16 + kq * 4 + v;
        const int col = wave * 64 + ni * 16 + row0;
        const int e = e0 + m;
        const float gz = FIRST ? 0.f : accZ[mi][ni][v];
        const float gh = FIRST ? 0.f : accH[mi][ni][v];
        const float zp = b2f(pre[(size_t)e * 768 + 256 + col]);
        const float hp = b2f(pre[(size_t)e * 768 + 512 + col]);
        const float z  = sigm(zp + gz);
        const float ph = tanh_f(hp + gh);
        const float shv = FIRST ? 0.f : b2f(sA[0][m][col]);
        float hn = (1.0f - z) * shv + z * ph;
        if (e == 0) hn = 0.f;                 // e_mask
        const u16 hb = f2b(hn);
        HBout[(size_t)e * 512 + col] = hb;
        sA[1][m][col] = hb;
      }
  __syncthreads();

  // hu = hnew @ Ur
  f32x4 accU[2][4];
#pragma unroll
  for (int i = 0; i < 2; ++i)
#pragma unroll
    for (int n = 0; n < 4; ++n) { accU[i][n][0]=0.f; accU[i][n][1]=0.f; accU[i][n][2]=0.f; accU[i][n][3]=0.f; }
#pragma unroll
  for (int s = 0; s < 8; ++s) {
    short8 a0 = *(const short8*)&sA[1][row0][s * 32 + kq * 8];
    short8 a1 = *(const short8*)&sA[1][row0 + 16][s * 32 + kq * 8];
#pragma unroll
    for (int ni = 0; ni < 4; ++ni) {
      short8 b = *(const short8*)(Urp + ((size_t)(s * 16 + wave * 4 + ni) * 64 + lane) * 8);
      accU[0][ni] = mfma16(a0, b, accU[0][ni]);
      accU[1][ni] = mfma16(a1, b, accU[1][ni]);
    }
  }
#pragma unroll
  for (int mi = 0; mi < 2; ++mi)
#pragma unroll
    for (int ni = 0; ni < 4; ++ni)
#pragma unroll
      for (int v = 0; v < 4; ++v) {
        const int m = mi * 16 + kq * 4 + v;
        const int col = wave * 64 + ni * 16 + row0;
        const int e = e0 + m;
        HBout[(size_t)e * 512 + 256 + col] = f2b(accU[mi][ni][v]);
      }
}

// ---------------- readout: out = relu([fnode | sum_k h[agraph]] @ Wo + bo) ----------------
__global__ __launch_bounds__(256)
void readout(const u16* __restrict__ HB, const u16* __restrict__ fnp,
             const int* __restrict__ agraph, const u16* __restrict__ Wop,
             const float* __restrict__ bo, float* __restrict__ out) {
  __shared__ __align__(16) u16 sN[32][264];
  const int tid = threadIdx.x, wave = tid >> 6, lane = tid & 63;
  const int n0 = blockIdx.x * 32;
  const int row0 = lane & 15, kq = lane >> 4;

#pragma unroll 2
  for (int rr = 0; rr < 8; ++rr) {
    const int r = wave * 8 + rr;
    const int n = n0 + r;
    float s4[4] = {0.f, 0.f, 0.f, 0.f};
    if (n < NN) {
#pragma unroll
      for (int k = 0; k < 6; ++k) {
        const int idx = agraph[n * 6 + k];
        const u16x4 hv = *(const u16x4*)(HB + (size_t)idx * 512 + 4 * lane);
#pragma unroll
        for (int j = 0; j < 4; ++j) s4[j] += b2f(hv[j]);
      }
    }
#pragma unroll
    for (int j = 0; j < 4; ++j) sN[r][4 * lane + j] = f2b(s4[j]);
  }
  __syncthreads();

  f32x4 acc[2][4];
#pragma unroll
  for (int i = 0; i < 2; ++i)
#pragma unroll
    for (int n = 0; n < 4; ++n) { acc[i][n][0]=0.f; acc[i][n][1]=0.f; acc[i][n][2]=0.f; acc[i][n][3]=0.f; }
  const int ra = min(n0 + row0, NN - 1);
  const int rb = min(n0 + 16 + row0, NN - 1);
#pragma unroll
  for (int s = 0; s < 12; ++s) {
    short8 a0, a1;
    if (s < 4) {
      a0 = *(const short8*)(fnp + (size_t)ra * 128 + s * 32 + kq * 8);
      a1 = *(const short8*)(fnp + (size_t)rb * 128 + s * 32 + kq * 8);
    } else {
      a0 = *(const short8*)&sN[row0][(s - 4) * 32 + kq * 8];
      a1 = *(const short8*)&sN[row0 + 16][(s - 4) * 32 + kq * 8];
    }
#pragma unroll
    for (int ni = 0; ni < 4; ++ni) {
      short8 b = *(const short8*)(Wop + ((size_t)(s * 16 + wave * 4 + ni) * 64 + lane) * 8);
      acc[0][ni] = mfma16(a0, b, acc[0][ni]);
      acc[1][ni] = mfma16(a1, b, acc[1][ni]);
    }
  }
#pragma unroll
  for (int mi = 0; mi < 2; ++mi)
#pragma unroll
    for (int ni = 0; ni < 4; ++ni)
#pragma unroll
      for (int v = 0; v < 4; ++v) {
        const int m = mi * 16 + kq * 4 + v;
        const int col = wave * 64 + ni * 16 + row0;
        const int n = n0 + m;
        if (n < NN) {
          float val = fmaxf(acc[mi][ni][v] + bo[col], 0.f);
          if (n == 0) val = 0.f;             // n_mask
          out[(size_t)n * 256 + col] = val;
        }
      }
}

extern "C" void kernel_launch(void* const* d_in, const int* in_sizes, int n_in,
                              void* d_out, int out_size, void* d_ws, size_t ws_size,
                              hipStream_t stream) {
  const float* fnode      = (const float*)d_in[0];
  const int*   fmess_idx  = (const int*)d_in[1];
  const float* fmess_feat = (const float*)d_in[2];
  const int*   agraph     = (const int*)d_in[3];
  const int*   bgraph     = (const int*)d_in[4];
  const float* Wz         = (const float*)d_in[5];
  const float* bz         = (const float*)d_in[6];
  const float* Wr         = (const float*)d_in[7];
  const float* Ur         = (const float*)d_in[8];
  const float* bur        = (const float*)d_in[9];
  const float* Wh         = (const float*)d_in[10];
  const float* bh         = (const float*)d_in[11];
  const float* Wo         = (const float*)d_in[12];
  const float* bo         = (const float*)d_in[13];
  float* out = (float*)d_out;

  char* ws = (char*)d_ws;
  size_t off = 0;
  auto carve = [&](size_t bytes) -> char* {
    char* p = ws + off;
    off += (bytes + 511) & ~(size_t)511;
    return p;
  };
  u16* HB0   = (u16*)carve((size_t)NE * 512 * 2);
  u16* HB1   = (u16*)carve((size_t)NE * 512 * 2);
  u16* pre   = (u16*)carve((size_t)NE * 768 * 2);
  u16* hmess = (u16*)carve((size_t)NE * 128 * 2);
  u16* fnp   = (u16*)carve((size_t)NN * 128 * 2);
  u16* wpre  = (u16*)carve((size_t)3 * 98304 * 2);
  u16* wgate = (u16*)carve((size_t)3 * 131072 * 2);
  u16* urp   = (u16*)carve((size_t)3 * 65536 * 2);
  u16* wop   = (u16*)carve((size_t)3 * 98304 * 2);
  if (off > ws_size) return;   // workspace too small -> visible clean failure

  pack_wpre <<<dim3(384, 3), 256, 0, stream>>>(Wr, Wz, Wh, wpre);
  pack_wgate<<<dim3(512, 3), 256, 0, stream>>>(Wz, Wh, wgate);
  pack_ur   <<<dim3(256, 3), 256, 0, stream>>>(Ur, urp);
  pack_wo   <<<dim3(384, 3), 256, 0, stream>>>(Wo, wop);
  embed_hmess<<<NE / 2, 256, 0, stream>>>(fnode, fmess_idx, fmess_feat, hmess);
  embed_fnode<<<NN / 2, 256, 0, stream>>>(fnode, fnp);

  for (int g = 0; g < 3; ++g) {
    pre_gemm<<<dim3(NE / 32, 3), 256, 0, stream>>>(
        hmess, wpre + (size_t)g * 98304, bur + g * 256, bz + g * 256, bh + g * 256, pre);
    const u16* wgate_g = wgate + (size_t)g * 131072;
    const u16* urp_g   = urp + (size_t)g * 65536;
    mpn_step<1><<<NE / 32, 256, 0, stream>>>(HB1, HB0, pre, bgraph, wgate_g, urp_g);
    u16* bufs[2] = {HB0, HB1};
    int cur = 0;
    for (int d = 1; d < 6; ++d) {
      mpn_step<0><<<NE / 32, 256, 0, stream>>>(bufs[cur], bufs[1 - cur], pre, bgraph, wgate_g, urp_g);
      cur ^= 1;
    }
    readout<<<(NN + 31) / 32, 256, 0, stream>>>(
        bufs[cur], fnp, agraph, wop + (size_t)g * 98304, bo + g * 256, out + (size_t)g * NN * 256);
  }
}